// Round 1
// baseline (6872.771 us; speedup 1.0000x reference)
//
#include <hip/hip_runtime.h>
#include <stdint.h>

typedef _Float16 f16;
typedef _Float16 h2 __attribute__((ext_vector_type(2)));
struct alignas(16) H8 { h2 h[4]; };

#if defined(__has_builtin)
#if __has_builtin(__builtin_amdgcn_fdot2)
#define FDOT2(a,b,c) __builtin_amdgcn_fdot2((a),(b),(c),false)
#endif
#endif
#ifndef FDOT2
static __device__ __forceinline__ float fdot2_sw(h2 a, h2 b, float c){
  return c + (float)a[0]*(float)b[0] + (float)a[1]*(float)b[1];
}
#define FDOT2(a,b,c) fdot2_sw((a),(b),(c))
#endif

static __device__ __forceinline__ float fast_tanh(float x){
  x = fminf(fmaxf(x, -30.f), 30.f);
  float e = __expf(-2.f*x);
  return (1.f - e)/(1.f + e);
}

// f16-element offsets inside d_ws
// L0: NK=15, R=464 -> 15*464*8 = 55680
// L1: NK=24, R=304 -> 24*304*8 = 58368
// L2: NK=18, R=256 -> 18*256*8 = 36864
#define WOFF0 0
#define WOFF1 55680
#define WOFF2 114048
#define WOFFO 150912   // woutT: 1024 h2 = 2048 f16

// ---------------- prep: pack masked weights to f16, lane-coalesced [kc][row][8] ----------------
__global__ __launch_bounds__(256) void cfc_prep(
    const float* __restrict__ W10,const float* __restrict__ W20,const float* __restrict__ Wa0,const float* __restrict__ Wb0,const int* __restrict__ M0,
    const float* __restrict__ W11,const float* __restrict__ W21,const float* __restrict__ Wa1,const float* __restrict__ Wb1,const int* __restrict__ M1,
    const float* __restrict__ W12,const float* __restrict__ W22,const float* __restrict__ Wa2,const float* __restrict__ Wb2,const int* __restrict__ M2,
    const float* __restrict__ Wo, f16* __restrict__ ws)
{
  int idx = blockIdx.x*256 + threadIdx.x;
  if (idx >= 19888) return;
  if (idx >= 18864) {               // pack Wout^T as [kpair][o] h2
    int i = idx - 18864, kp = i >> 5, o = i & 31;
    h2 v; v[0] = (f16)Wo[o*64 + 2*kp]; v[1] = (f16)Wo[o*64 + 2*kp + 1];
    ((h2*)(ws + WOFFO))[i] = v;
    return;
  }
  int base, R, c, h, woff;
  const float* W[4]; const int* M;
  if (idx < 6960){      base=idx;       R=464; c=117; h=116; woff=WOFF0; W[0]=W10;W[1]=W20;W[2]=Wa0;W[3]=Wb0; M=M0; }
  else if (idx < 14256){base=idx-6960;  R=304; c=192; h=76;  woff=WOFF1; W[0]=W11;W[1]=W21;W[2]=Wa1;W[3]=Wb1; M=M1; }
  else {                base=idx-14256; R=256; c=140; h=64;  woff=WOFF2; W[0]=W12;W[1]=W22;W[2]=Wa2;W[3]=Wb2; M=M2; }
  int kc = base / R, r = base % R;
  int m = r / h, n = r % h;
  const float* Wm = W[m];
  H8 hh; f16* p = (f16*)&hh;
  #pragma unroll
  for (int j=0;j<8;++j){
    int k = kc*8 + j;
    float v = 0.f;
    if (k < c){ v = Wm[n*c + k]; if (m < 2) v *= (float)M[n*c + k]; }
    p[j] = (f16)v;
  }
  ((H8*)(ws + woff))[(size_t)kc*R + r] = hh;
}

// ---------------- main persistent recurrence kernel ----------------
__global__ __launch_bounds__(512) void cfc_main(
    const float* __restrict__ dtp, const float* __restrict__ hxp,
    const float* __restrict__ b10,const float* __restrict__ b20,const float* __restrict__ ba0,const float* __restrict__ bb0,
    const float* __restrict__ b11,const float* __restrict__ b21,const float* __restrict__ ba1,const float* __restrict__ bb1,
    const float* __restrict__ b12,const float* __restrict__ b22,const float* __restrict__ ba2,const float* __restrict__ bb2,
    const float* __restrict__ boutp, const f16* __restrict__ ws, float* __restrict__ outp)
{
  const int wg  = blockIdx.x;     // 0..127
  const int tid = threadIdx.x;    // 0..511
  const int gb0 = wg*4;

  __shared__ alignas(16) h2 xbuf[3][4][96];   // x0:[dt,h0] 60 cells | x1:[h0,h1] 96 | x2:[h1,h2] 72
  __shared__ float pre[2][4][4][116];         // [khalf][mat][b][n]
  __shared__ float bias[3][4][116];
  __shared__ h2    woutT[1024];               // [kpair][o]
  __shared__ float bout_s[32];
  __shared__ float dts[4][1024];

  for (int i=tid;i<3*4*96;i+=512) ((float*)xbuf)[i]=0.f;
  for (int i=tid;i<4096;i+=512){int b=i>>10,t=i&1023; dts[b][t]=dtp[(size_t)(gb0+b)*1024+t];}
  for (int n=tid;n<116;n+=512){bias[0][0][n]=b10[n];bias[0][1][n]=b20[n];bias[0][2][n]=ba0[n];bias[0][3][n]=bb0[n];}
  for (int n=tid;n<76; n+=512){bias[1][0][n]=b11[n];bias[1][1][n]=b21[n];bias[1][2][n]=ba1[n];bias[1][3][n]=bb1[n];}
  for (int n=tid;n<64; n+=512){bias[2][0][n]=b12[n];bias[2][1][n]=b22[n];bias[2][2][n]=ba2[n];bias[2][3][n]=bb2[n];}
  for (int i=tid;i<1024;i+=512) woutT[i]=((const h2*)(ws+WOFFO))[i];
  if (tid<32) bout_s[tid]=boutp[tid];
  __syncthreads();
  for (int i=tid;i<1024;i+=512){
    int b=i>>8,u=i&255;
    f16 hv=(f16)hxp[(size_t)(gb0+b)*256+u];
    if (u<116){ ((f16*)xbuf[0][b])[1+u]=hv; ((f16*)xbuf[1][b])[u]=hv; }
    else if (u<192){int n=u-116; ((f16*)xbuf[1][b])[116+n]=hv; ((f16*)xbuf[2][b])[n]=hv;}
    else {int n=u-192; ((f16*)xbuf[2][b])[76+n]=hv;}
  }
  __syncthreads();

  const H8* w0=(const H8*)(ws+WOFF0);
  const H8* w1=(const H8*)(ws+WOFF1);
  const H8* w2=(const H8*)(ws+WOFF2);

  for (int t=0;t<1024;++t){
    if (tid<4) ((f16*)xbuf[0][tid])[0]=(f16)dts[tid][t];
    __syncthreads();

    // ---------- layer 0: full rows, NK=15, R=464 ----------
    if (tid<464){
      const int r=tid;
      const H8* xA=(const H8*)xbuf[0][0]; const H8* xB=(const H8*)xbuf[0][1];
      const H8* xC=(const H8*)xbuf[0][2]; const H8* xD=(const H8*)xbuf[0][3];
      float a0=0,a1=0,a2=0,a3=0;
      #pragma unroll
      for (int kc=0;kc<15;++kc){
        H8 w=w0[kc*464+r];
        H8 p0=xA[kc],p1=xB[kc],p2=xC[kc],p3=xD[kc];
        #pragma unroll
        for (int q=0;q<4;++q){
          a0=FDOT2(w.h[q],p0.h[q],a0); a1=FDOT2(w.h[q],p1.h[q],a1);
          a2=FDOT2(w.h[q],p2.h[q],a2); a3=FDOT2(w.h[q],p3.h[q],a3);
        }
      }
      const int m=r/116, n=r%116;
      pre[0][m][0][n]=a0; pre[0][m][1][n]=a1; pre[0][m][2][n]=a2; pre[0][m][3][n]=a3;
    }
    __syncthreads();
    if (tid<464){
      const int b=tid/116, n=tid%116;
      float p1=pre[0][0][b][n]+bias[0][0][n];
      float p2=pre[0][1][b][n]+bias[0][1][n];
      float pa=pre[0][2][b][n]+bias[0][2][n];
      float pb=pre[0][3][b][n]+bias[0][3][n];
      float s=1.f/(1.f+__expf(-(pa+pb)));
      float f1=fast_tanh(p1), f2=fast_tanh(p2);
      f16 hv=(f16)(f1 + s*(f2-f1));
      ((f16*)xbuf[0][b])[1+n]=hv;
      ((f16*)xbuf[1][b])[n]=hv;
    }
    __syncthreads();

    // ---------- layer 1: K-halved rows, NKh=12, R=304 ----------
    {
      const int hf=tid>>8, r=tid&255, kc0=hf*12;   // halves (hf, r) for r<256
      const H8* xA=(const H8*)xbuf[1][0]; const H8* xB=(const H8*)xbuf[1][1];
      const H8* xC=(const H8*)xbuf[1][2]; const H8* xD=(const H8*)xbuf[1][3];
      float a0=0,a1=0,a2=0,a3=0;
      #pragma unroll
      for (int kc=0;kc<12;++kc){
        H8 w=w1[(kc0+kc)*304+r];
        H8 p0=xA[kc0+kc],p1=xB[kc0+kc],p2=xC[kc0+kc],p3=xD[kc0+kc];
        #pragma unroll
        for (int q=0;q<4;++q){
          a0=FDOT2(w.h[q],p0.h[q],a0); a1=FDOT2(w.h[q],p1.h[q],a1);
          a2=FDOT2(w.h[q],p2.h[q],a2); a3=FDOT2(w.h[q],p3.h[q],a3);
        }
      }
      const int m=r/76, n=r%76;
      pre[hf][m][0][n]=a0; pre[hf][m][1][n]=a1; pre[hf][m][2][n]=a2; pre[hf][m][3][n]=a3;
    }
    if (tid<96){   // leftover halves for rows 256..303
      const int r=256+(tid>>1), hf=tid&1, kc0=hf*12;
      const H8* xA=(const H8*)xbuf[1][0]; const H8* xB=(const H8*)xbuf[1][1];
      const H8* xC=(const H8*)xbuf[1][2]; const H8* xD=(const H8*)xbuf[1][3];
      float a0=0,a1=0,a2=0,a3=0;
      #pragma unroll
      for (int kc=0;kc<12;++kc){
        H8 w=w1[(kc0+kc)*304+r];
        H8 p0=xA[kc0+kc],p1=xB[kc0+kc],p2=xC[kc0+kc],p3=xD[kc0+kc];
        #pragma unroll
        for (int q=0;q<4;++q){
          a0=FDOT2(w.h[q],p0.h[q],a0); a1=FDOT2(w.h[q],p1.h[q],a1);
          a2=FDOT2(w.h[q],p2.h[q],a2); a3=FDOT2(w.h[q],p3.h[q],a3);
        }
      }
      const int m=r/76, n=r%76;
      pre[hf][m][0][n]=a0; pre[hf][m][1][n]=a1; pre[hf][m][2][n]=a2; pre[hf][m][3][n]=a3;
    }
    __syncthreads();
    if (tid<304){
      const int b=tid/76, n=tid%76;
      float p1=pre[0][0][b][n]+pre[1][0][b][n]+bias[1][0][n];
      float p2=pre[0][1][b][n]+pre[1][1][b][n]+bias[1][1][n];
      float pa=pre[0][2][b][n]+pre[1][2][b][n]+bias[1][2][n];
      float pb=pre[0][3][b][n]+pre[1][3][b][n]+bias[1][3][n];
      float s=1.f/(1.f+__expf(-(pa+pb)));
      float f1=fast_tanh(p1), f2=fast_tanh(p2);
      f16 hv=(f16)(f1 + s*(f2-f1));
      ((f16*)xbuf[1][b])[116+n]=hv;
      ((f16*)xbuf[2][b])[n]=hv;
    }
    __syncthreads();

    // ---------- layer 2: K-halved rows, NKh=9, R=256 ----------
    {
      const int hf=tid>>8, r=tid&255, kc0=hf*9;
      const H8* xA=(const H8*)xbuf[2][0]; const H8* xB=(const H8*)xbuf[2][1];
      const H8* xC=(const H8*)xbuf[2][2]; const H8* xD=(const H8*)xbuf[2][3];
      float a0=0,a1=0,a2=0,a3=0;
      #pragma unroll
      for (int kc=0;kc<9;++kc){
        H8 w=w2[(kc0+kc)*256+r];
        H8 p0=xA[kc0+kc],p1=xB[kc0+kc],p2=xC[kc0+kc],p3=xD[kc0+kc];
        #pragma unroll
        for (int q=0;q<4;++q){
          a0=FDOT2(w.h[q],p0.h[q],a0); a1=FDOT2(w.h[q],p1.h[q],a1);
          a2=FDOT2(w.h[q],p2.h[q],a2); a3=FDOT2(w.h[q],p3.h[q],a3);
        }
      }
      const int m=r>>6, n=r&63;
      pre[hf][m][0][n]=a0; pre[hf][m][1][n]=a1; pre[hf][m][2][n]=a2; pre[hf][m][3][n]=a3;
    }
    __syncthreads();
    if (tid<256){
      const int b=tid>>6, n=tid&63;
      float p1=pre[0][0][b][n]+pre[1][0][b][n]+bias[2][0][n];
      float p2=pre[0][1][b][n]+pre[1][1][b][n]+bias[2][1][n];
      float pa=pre[0][2][b][n]+pre[1][2][b][n]+bias[2][2][n];
      float pb=pre[0][3][b][n]+pre[1][3][b][n]+bias[2][3][n];
      float s=1.f/(1.f+__expf(-(pa+pb)));
      float f1=fast_tanh(p1), f2=fast_tanh(p2);
      f16 hv=(f16)(f1 + s*(f2-f1));
      ((f16*)xbuf[2][b])[76+n]=hv;
    }
    __syncthreads();

    // ---------- readout: (4 x 64) @ Wout^T + bout ----------
    if (tid<128){
      const int b=tid>>5, o=tid&31;
      float acc=bout_s[o];
      const h2* hh=(const h2*)(xbuf[2][b]+38);   // h2 part of x2 (f16 idx 76..139)
      #pragma unroll
      for (int kp=0;kp<32;++kp) acc=FDOT2(hh[kp],woutT[kp*32+o],acc);
      outp[((gb0+b)*1024+t)*32+o]=acc;
    }
  }
}

extern "C" void kernel_launch(void* const* d_in, const int* in_sizes, int n_in,
                              void* d_out, int out_size, void* d_ws, size_t ws_size,
                              hipStream_t stream)
{
  (void)in_sizes; (void)n_in; (void)out_size; (void)ws_size;
  f16* ws = (f16*)d_ws;
  cfc_prep<<<78,256,0,stream>>>(
    (const float*)d_in[2],(const float*)d_in[3],(const float*)d_in[4],(const float*)d_in[5],(const int*)d_in[10],
    (const float*)d_in[11],(const float*)d_in[12],(const float*)d_in[13],(const float*)d_in[14],(const int*)d_in[19],
    (const float*)d_in[20],(const float*)d_in[21],(const float*)d_in[22],(const float*)d_in[23],(const int*)d_in[28],
    (const float*)d_in[29], ws);
  cfc_main<<<128,512,0,stream>>>(
    (const float*)d_in[0],(const float*)d_in[1],
    (const float*)d_in[6],(const float*)d_in[7],(const float*)d_in[8],(const float*)d_in[9],
    (const float*)d_in[15],(const float*)d_in[16],(const float*)d_in[17],(const float*)d_in[18],
    (const float*)d_in[24],(const float*)d_in[25],(const float*)d_in[26],(const float*)d_in[27],
    (const float*)d_in[30], ws, (float*)d_out);
}

// Round 2
// 2836.071 us; speedup vs baseline: 2.4233x; 2.4233x over previous
//
#include <hip/hip_runtime.h>
#include <stdint.h>

typedef _Float16 f16;
typedef _Float16 h2 __attribute__((ext_vector_type(2)));
struct alignas(16) H8 { h2 h[4]; };

#if defined(__has_builtin)
#if __has_builtin(__builtin_amdgcn_fdot2)
#define FDOT2(a,b,c) __builtin_amdgcn_fdot2((a),(b),(c),false)
#endif
#endif
#ifndef FDOT2
static __device__ __forceinline__ float fdot2_sw(h2 a, h2 b, float c){
  return c + (float)a[0]*(float)b[0] + (float)a[1]*(float)b[1];
}
#define FDOT2(a,b,c) fdot2_sw((a),(b),(c))
#endif

static __device__ __forceinline__ float fast_tanh(float x){
  x = fminf(fmaxf(x, -30.f), 30.f);
  float e = __expf(-2.f*x);
  return (1.f - e)/(1.f + e);
}
static __device__ __forceinline__ float sigm(float x){ return 1.f/(1.f+__expf(-x)); }

// f16-element offsets inside d_ws
// L0: NK=15, R=464 -> 15*464*8 = 55680
// L1: NK=24, R=304 -> 24*304*8 = 58368
// L2: NK=18, R=256 -> 18*256*8 = 36864
#define WOFF0 0
#define WOFF1 55680
#define WOFF2 114048
#define WOFFO 150912   // woutT: 1024 h2

// ---------------- prep: pack masked weights to f16, [kc][row] H8 chunks ----------------
__global__ __launch_bounds__(256) void cfc_prep(
    const float* __restrict__ W10,const float* __restrict__ W20,const float* __restrict__ Wa0,const float* __restrict__ Wb0,const int* __restrict__ M0,
    const float* __restrict__ W11,const float* __restrict__ W21,const float* __restrict__ Wa1,const float* __restrict__ Wb1,const int* __restrict__ M1,
    const float* __restrict__ W12,const float* __restrict__ W22,const float* __restrict__ Wa2,const float* __restrict__ Wb2,const int* __restrict__ M2,
    const float* __restrict__ Wo, f16* __restrict__ ws)
{
  int idx = blockIdx.x*256 + threadIdx.x;
  if (idx >= 19888) return;
  if (idx >= 18864) {               // pack Wout^T as [kpair][o] h2
    int i = idx - 18864, kp = i >> 5, o = i & 31;
    h2 v; v[0] = (f16)Wo[o*64 + 2*kp]; v[1] = (f16)Wo[o*64 + 2*kp + 1];
    ((h2*)(ws + WOFFO))[i] = v;
    return;
  }
  int base, R, c, h, woff;
  const float* W[4]; const int* M;
  if (idx < 6960){      base=idx;       R=464; c=117; h=116; woff=WOFF0; W[0]=W10;W[1]=W20;W[2]=Wa0;W[3]=Wb0; M=M0; }
  else if (idx < 14256){base=idx-6960;  R=304; c=192; h=76;  woff=WOFF1; W[0]=W11;W[1]=W21;W[2]=Wa1;W[3]=Wb1; M=M1; }
  else {                base=idx-14256; R=256; c=140; h=64;  woff=WOFF2; W[0]=W12;W[1]=W22;W[2]=Wa2;W[3]=Wb2; M=M2; }
  int kc = base / R, r = base % R;
  int m = r / h, n = r % h;
  const float* Wm = W[m];
  H8 hh; f16* p = (f16*)&hh;
  #pragma unroll
  for (int j=0;j<8;++j){
    int k = kc*8 + j;
    float v = 0.f;
    if (k < c){ v = Wm[n*c + k]; if (m < 2) v *= (float)M[n*c + k]; }
    p[j] = (f16)v;
  }
  ((H8*)(ws + woff))[(size_t)kc*R + r] = hh;
}

// ---------------- main persistent recurrence kernel: weights in registers ----------------
// 256 WGs x 512 threads x 2 batch rows. Per-thread static weight ownership:
//   L0: row tid (tid<464), 15 chunks (60 VGPR)
//   L1: slot0 = tid, slot1 = tid+512 (valid tid<400); slot=(third,row), 8 chunks each (64 VGPR)
//   L2: slot tid = (half=tid>>8, row=tid&255), 9 chunks (36 VGPR)
__global__ __launch_bounds__(512, 2) void cfc_main(
    const float* __restrict__ dtp, const float* __restrict__ hxp,
    const float* __restrict__ b10,const float* __restrict__ b20,const float* __restrict__ ba0,const float* __restrict__ bb0,
    const float* __restrict__ b11,const float* __restrict__ b21,const float* __restrict__ ba1,const float* __restrict__ bb1,
    const float* __restrict__ b12,const float* __restrict__ b22,const float* __restrict__ ba2,const float* __restrict__ bb2,
    const float* __restrict__ boutp, const f16* __restrict__ ws, float* __restrict__ outp)
{
  const int tid = threadIdx.x;
  const int gb0 = blockIdx.x*2;

  __shared__ alignas(16) h2 xbuf[3][2][96];   // x0:[dt,h0] | x1:[h0,h1] | x2:[h1,h2]
  __shared__ float preb[1920];                // aliased partial buffers (L0: 8x120 | L1: 3x8x80 | L2: 2x8x64)
  __shared__ float bias[3][4][120];
  __shared__ h2    woutT[1024];               // [kpair][o]
  __shared__ float bout_s[32];
  __shared__ float dts[2][1024];

  const H8* w0=(const H8*)(ws+WOFF0);
  const H8* w1=(const H8*)(ws+WOFF1);
  const H8* w2=(const H8*)(ws+WOFF2);

  // ---- weight register loads (coalesced: consecutive tid -> consecutive 16B) ----
  H8 wl0[15];
  const int m0 = tid/116, n0 = tid%116;
  if (tid < 464){
    #pragma unroll
    for (int kc=0;kc<15;++kc) wl0[kc]=w0[kc*464+tid];
  }
  const int t1a = (tid<304)?0:1, r1a = (tid<304)?tid:(tid-304);
  H8 wl1a[8];
  #pragma unroll
  for (int kc=0;kc<8;++kc) wl1a[kc]=w1[(t1a*8+kc)*304+r1a];
  const int s1b = tid+512;
  const bool has_b = (tid<400);
  const int t1b = s1b/304, r1b = s1b%304;
  H8 wl1b[8];
  if (has_b){
    #pragma unroll
    for (int kc=0;kc<8;++kc) wl1b[kc]=w1[(t1b*8+kc)*304+r1b];
  }
  const int mA = r1a/76, nA = r1a%76;
  const int mB = r1b/76, nB = r1b%76;
  const int hf2 = tid>>8, r2 = tid&255;
  H8 wl2[9];
  #pragma unroll
  for (int kc=0;kc<9;++kc) wl2[kc]=w2[(hf2*9+kc)*256+r2];
  const int m2 = r2>>6, n2 = r2&63;

  // ---- LDS init ----
  for (int i=tid;i<576;i+=512) ((float*)xbuf)[i]=0.f;
  for (int i=tid;i<2048;i+=512) dts[i>>10][i&1023]=dtp[(size_t)(gb0+(i>>10))*1024+(i&1023)];
  for (int n=tid;n<116;n+=512){bias[0][0][n]=b10[n];bias[0][1][n]=b20[n];bias[0][2][n]=ba0[n];bias[0][3][n]=bb0[n];}
  for (int n=tid;n<76; n+=512){bias[1][0][n]=b11[n];bias[1][1][n]=b21[n];bias[1][2][n]=ba1[n];bias[1][3][n]=bb1[n];}
  for (int n=tid;n<64; n+=512){bias[2][0][n]=b12[n];bias[2][1][n]=b22[n];bias[2][2][n]=ba2[n];bias[2][3][n]=bb2[n];}
  for (int i=tid;i<1024;i+=512) woutT[i]=((const h2*)(ws+WOFFO))[i];
  if (tid<32) bout_s[tid]=boutp[tid];
  __syncthreads();
  {
    int b=tid>>8, u=tid&255;
    f16 hv=(f16)hxp[(size_t)(gb0+b)*256+u];
    if (u<116){ ((f16*)xbuf[0][b])[1+u]=hv; ((f16*)xbuf[1][b])[u]=hv; }
    else if (u<192){int n=u-116; ((f16*)xbuf[1][b])[116+n]=hv; ((f16*)xbuf[2][b])[n]=hv;}
    else {int n=u-192; ((f16*)xbuf[2][b])[76+n]=hv;}
  }
  if (tid<2) ((f16*)xbuf[0][tid])[0]=(f16)dts[tid][0];
  __syncthreads();

  const H8* xA0=(const H8*)xbuf[0][0]; const H8* xA1=(const H8*)xbuf[0][1];
  const H8* xB0=(const H8*)xbuf[1][0]; const H8* xB1=(const H8*)xbuf[1][1];
  const H8* xC0=(const H8*)xbuf[2][0]; const H8* xC1=(const H8*)xbuf[2][1];

  for (int t=0;t<1024;++t){
    // ---------- Phase A: L0 dots ----------
    if (tid<464){
      float a0=0.f,a1=0.f;
      #pragma unroll
      for (int kc=0;kc<15;++kc){
        H8 p0=xA0[kc], p1=xA1[kc];
        #pragma unroll
        for (int q=0;q<4;++q){ a0=FDOT2(wl0[kc].h[q],p0.h[q],a0); a1=FDOT2(wl0[kc].h[q],p1.h[q],a1); }
      }
      preb[(m0*2+0)*120+n0]=a0; preb[(m0*2+1)*120+n0]=a1;
    }
    __syncthreads();
    // ---------- Phase B: act L0 (writes h0); dt prefetch ----------
    if (tid<232){
      int b=tid/116, n=tid%116;
      float p1=preb[(0*2+b)*120+n]+bias[0][0][n];
      float p2=preb[(1*2+b)*120+n]+bias[0][1][n];
      float pa=preb[(2*2+b)*120+n]+bias[0][2][n];
      float pb=preb[(3*2+b)*120+n]+bias[0][3][n];
      float s=sigm(pa+pb);
      float f1=fast_tanh(p1), f2=fast_tanh(p2);
      f16 hv=(f16)(f1 + s*(f2-f1));
      ((f16*)xbuf[0][b])[1+n]=hv;
      ((f16*)xbuf[1][b])[n]=hv;
    } else if (tid>=256 && tid<258){
      if (t+1<1024) ((f16*)xbuf[0][tid-256])[0]=(f16)dts[tid-256][t+1];
    }
    __syncthreads();
    // ---------- Phase C: L1 dots (2 slots/thread) ----------
    {
      float a0=0.f,a1=0.f;
      #pragma unroll
      for (int kc=0;kc<8;++kc){
        int g=t1a*8+kc;
        H8 p0=xB0[g], p1=xB1[g];
        #pragma unroll
        for (int q=0;q<4;++q){ a0=FDOT2(wl1a[kc].h[q],p0.h[q],a0); a1=FDOT2(wl1a[kc].h[q],p1.h[q],a1); }
      }
      preb[((t1a*4+mA)*2+0)*80+nA]=a0; preb[((t1a*4+mA)*2+1)*80+nA]=a1;
    }
    if (has_b){
      float a0=0.f,a1=0.f;
      #pragma unroll
      for (int kc=0;kc<8;++kc){
        int g=t1b*8+kc;
        H8 p0=xB0[g], p1=xB1[g];
        #pragma unroll
        for (int q=0;q<4;++q){ a0=FDOT2(wl1b[kc].h[q],p0.h[q],a0); a1=FDOT2(wl1b[kc].h[q],p1.h[q],a1); }
      }
      preb[((t1b*4+mB)*2+0)*80+nB]=a0; preb[((t1b*4+mB)*2+1)*80+nB]=a1;
    }
    __syncthreads();
    // ---------- Phase D: act L1 (writes h1) + readout of step t-1 ----------
    if (tid<152){
      int b=tid/76, n=tid%76;
      float p1=preb[((0*4+0)*2+b)*80+n]+preb[((1*4+0)*2+b)*80+n]+preb[((2*4+0)*2+b)*80+n]+bias[1][0][n];
      float p2=preb[((0*4+1)*2+b)*80+n]+preb[((1*4+1)*2+b)*80+n]+preb[((2*4+1)*2+b)*80+n]+bias[1][1][n];
      float pa=preb[((0*4+2)*2+b)*80+n]+preb[((1*4+2)*2+b)*80+n]+preb[((2*4+2)*2+b)*80+n]+bias[1][2][n];
      float pb=preb[((0*4+3)*2+b)*80+n]+preb[((1*4+3)*2+b)*80+n]+preb[((2*4+3)*2+b)*80+n]+bias[1][3][n];
      float s=sigm(pa+pb);
      float f1=fast_tanh(p1), f2=fast_tanh(p2);
      f16 hv=(f16)(f1 + s*(f2-f1));
      ((f16*)xbuf[1][b])[116+n]=hv;
      ((f16*)xbuf[2][b])[n]=hv;
    } else if (tid>=192 && tid<224 && t>0){
      int o=tid-192;
      float ac0=bout_s[o], ac1=ac0;
      const h2* hh0=(const h2*)xbuf[2][0]+38;   // h2 part (f16 idx 76..139) of step t-1
      const h2* hh1=(const h2*)xbuf[2][1]+38;
      #pragma unroll
      for (int kp=0;kp<32;++kp){ h2 wv=woutT[kp*32+o]; ac0=FDOT2(hh0[kp],wv,ac0); ac1=FDOT2(hh1[kp],wv,ac1); }
      outp[((size_t)(gb0+0)*1024+(t-1))*32+o]=ac0;
      outp[((size_t)(gb0+1)*1024+(t-1))*32+o]=ac1;
    }
    __syncthreads();
    // ---------- Phase E: L2 dots ----------
    {
      float a0=0.f,a1=0.f;
      #pragma unroll
      for (int kc=0;kc<9;++kc){
        int g=hf2*9+kc;
        H8 p0=xC0[g], p1=xC1[g];
        #pragma unroll
        for (int q=0;q<4;++q){ a0=FDOT2(wl2[kc].h[q],p0.h[q],a0); a1=FDOT2(wl2[kc].h[q],p1.h[q],a1); }
      }
      preb[((hf2*4+m2)*2+0)*64+n2]=a0; preb[((hf2*4+m2)*2+1)*64+n2]=a1;
    }
    __syncthreads();
    // ---------- Phase F: act L2 (writes h2) ----------
    if (tid<128){
      int b=tid>>6, n=tid&63;
      float p1=preb[((0*4+0)*2+b)*64+n]+preb[((1*4+0)*2+b)*64+n]+bias[2][0][n];
      float p2=preb[((0*4+1)*2+b)*64+n]+preb[((1*4+1)*2+b)*64+n]+bias[2][1][n];
      float pa=preb[((0*4+2)*2+b)*64+n]+preb[((1*4+2)*2+b)*64+n]+bias[2][2][n];
      float pb=preb[((0*4+3)*2+b)*64+n]+preb[((1*4+3)*2+b)*64+n]+bias[2][3][n];
      float s=sigm(pa+pb);
      float f1=fast_tanh(p1), f2=fast_tanh(p2);
      f16 hv=(f16)(f1 + s*(f2-f1));
      ((f16*)xbuf[2][b])[76+n]=hv;
    }
    __syncthreads();
  }
  // ---------- tail readout for t=1023 ----------
  if (tid>=192 && tid<224){
    int o=tid-192;
    float ac0=bout_s[o], ac1=ac0;
    const h2* hh0=(const h2*)xbuf[2][0]+38;
    const h2* hh1=(const h2*)xbuf[2][1]+38;
    #pragma unroll
    for (int kp=0;kp<32;++kp){ h2 wv=woutT[kp*32+o]; ac0=FDOT2(hh0[kp],wv,ac0); ac1=FDOT2(hh1[kp],wv,ac1); }
    outp[((size_t)(gb0+0)*1024+1023)*32+o]=ac0;
    outp[((size_t)(gb0+1)*1024+1023)*32+o]=ac1;
  }
}

extern "C" void kernel_launch(void* const* d_in, const int* in_sizes, int n_in,
                              void* d_out, int out_size, void* d_ws, size_t ws_size,
                              hipStream_t stream)
{
  (void)in_sizes; (void)n_in; (void)out_size; (void)ws_size;
  f16* ws = (f16*)d_ws;
  cfc_prep<<<78,256,0,stream>>>(
    (const float*)d_in[2],(const float*)d_in[3],(const float*)d_in[4],(const float*)d_in[5],(const int*)d_in[10],
    (const float*)d_in[11],(const float*)d_in[12],(const float*)d_in[13],(const float*)d_in[14],(const int*)d_in[19],
    (const float*)d_in[20],(const float*)d_in[21],(const float*)d_in[22],(const float*)d_in[23],(const int*)d_in[28],
    (const float*)d_in[29], ws);
  cfc_main<<<256,512,0,stream>>>(
    (const float*)d_in[0],(const float*)d_in[1],
    (const float*)d_in[6],(const float*)d_in[7],(const float*)d_in[8],(const float*)d_in[9],
    (const float*)d_in[15],(const float*)d_in[16],(const float*)d_in[17],(const float*)d_in[18],
    (const float*)d_in[24],(const float*)d_in[25],(const float*)d_in[26],(const float*)d_in[27],
    (const float*)d_in[30], ws, (float*)d_out);
}